// Round 3
// baseline (123.773 us; speedup 1.0000x reference)
//
#include <hip/hip_runtime.h>

#define N_CLASS_C 6

// Native vector types (HIP's int4/float4 are structs -> not accepted by
// __builtin_nontemporal_load).
typedef int   vint4  __attribute__((ext_vector_type(4)));
typedef float vfloat4 __attribute__((ext_vector_type(4)));

// ---------------- ws header layout ----------------
// [0..24)   : accum[6] floats
// [24..28)  : overflow/list counter (unsigned)
// [256..)   : atoms float4 table (256B aligned)
// then      : gidx[cap] ints, base4[cap] vfloat4 (16B aligned)

__global__ void zero_hdr(float* accum, unsigned* counter) {
    if (threadIdx.x < N_CLASS_C) accum[threadIdx.x] = 0.0f;
    if (threadIdx.x == 0) *counter = 0u;
}

__global__ void prep_atoms(const float* __restrict__ coords,
                           const float* __restrict__ radii,
                           const int* __restrict__ names,
                           vfloat4* __restrict__ atoms,
                           int n_atoms) {
    int i = blockIdx.x * blockDim.x + threadIdx.x;
    if (i < n_atoms) {
        vfloat4 a;
        a.x = coords[3 * i + 0];
        a.y = coords[3 * i + 1];
        a.z = coords[3 * i + 2];
        a.w = radii[names[i]];
        atoms[i] = a;
    }
}

__device__ __forceinline__ void block_reduce_accum(float* s, float* accum) {
    __shared__ float sh[N_CLASS_C];
    if (threadIdx.x < N_CLASS_C) sh[threadIdx.x] = 0.0f;
    __syncthreads();
#pragma unroll
    for (int c = 0; c < N_CLASS_C; ++c) {
        float v = s[c];
#pragma unroll
        for (int off = 32; off > 0; off >>= 1) v += __shfl_down(v, off, 64);
        if ((threadIdx.x & 63) == 0 && v != 0.0f) atomicAdd(&sh[c], v);
    }
    __syncthreads();
    if (threadIdx.x < N_CLASS_C) {
        float v = sh[threadIdx.x];
        if (v != 0.0f) atomicAdd(&accum[threadIdx.x], v);
    }
}

// Phase A: distances + compaction of qualifying groups. Mask loads only on
// list overflow (correctness fallback) and tail pairs.
__global__ __launch_bounds__(256) void phaseA(
    const int* __restrict__ pairs,      // 2 * n_pairs
    const vfloat4* __restrict__ atoms,
    const int* __restrict__ masks,
    const float* __restrict__ tol,
    float* __restrict__ accum,
    unsigned* __restrict__ counter,
    int* __restrict__ gidx,
    vfloat4* __restrict__ base4,
    unsigned cap,
    int n_pairs) {
    float tc[N_CLASS_C];
#pragma unroll
    for (int c = 0; c < N_CLASS_C; ++c) tc[c] = tol[c];
    float tmax = tc[0];
#pragma unroll
    for (int c = 1; c < N_CLASS_C; ++c) tmax = fmaxf(tmax, tc[c]);

    float s[N_CLASS_C];
#pragma unroll
    for (int c = 0; c < N_CLASS_C; ++c) s[c] = 0.0f;

    const int ngroups = n_pairs >> 2;
    const int tid = blockIdx.x * blockDim.x + threadIdx.x;
    const int stride = gridDim.x * blockDim.x;
    const int lane = threadIdx.x & 63;
    const vint4* pairs4 = reinterpret_cast<const vint4*>(pairs);

    for (int g = tid; g < ngroups; g += stride) {
        // Streaming reads: nontemporal so they don't evict the atoms table
        // from L2.
        vint4 pa = __builtin_nontemporal_load(&pairs4[2 * g]);
        vint4 pb = __builtin_nontemporal_load(&pairs4[2 * g + 1]);
        int i0[4] = {pa.x, pa.z, pb.x, pb.z};
        int i1[4] = {pa.y, pa.w, pb.y, pb.w};
        float base[4];
#pragma unroll
        for (int j = 0; j < 4; ++j) {
            vfloat4 A = atoms[i0[j]];
            vfloat4 B = atoms[i1[j]];
            float dx = A.x - B.x, dy = A.y - B.y, dz = A.z - B.z;
            float dist = sqrtf(dx * dx + dy * dy + dz * dz + 1e-12f);
            base[j] = (A.w + B.w) - dist;
        }
        float bm = fmaxf(fmaxf(base[0], base[1]), fmaxf(base[2], base[3]));
        bool pred = (bm + tmax > 0.0f);
        unsigned long long m = __ballot(pred);
        if (pred) {
            int leader = __ffsll((unsigned long long)m) - 1;
            int rank = __popcll(m & ((1ull << lane) - 1ull));
            unsigned basep = 0;
            if (lane == leader) basep = atomicAdd(counter, (unsigned)__popcll(m));
            basep = (unsigned)__shfl((int)basep, leader, 64);
            unsigned slot = basep + (unsigned)rank;
            if (slot < cap) {
                gidx[slot] = g;
                vfloat4 b4;
                b4.x = base[0]; b4.y = base[1]; b4.z = base[2]; b4.w = base[3];
                base4[slot] = b4;
            } else {
                // Overflow: process inline (rare / never for expected data).
#pragma unroll
                for (int c = 0; c < N_CLASS_C; ++c) {
                    vint4 mm = __builtin_nontemporal_load(
                        &reinterpret_cast<const vint4*>(masks + (size_t)c * n_pairs)[g]);
                    float acc = 0.0f;
                    if (mm.x) acc += fmaxf(base[0] + tc[c], 0.0f);
                    if (mm.y) acc += fmaxf(base[1] + tc[c], 0.0f);
                    if (mm.z) acc += fmaxf(base[2] + tc[c], 0.0f);
                    if (mm.w) acc += fmaxf(base[3] + tc[c], 0.0f);
                    s[c] += acc;
                }
            }
        }
    }

    // Tail pairs (n_pairs % 4 != 0): full inline path.
    for (int p = (ngroups << 2) + tid; p < n_pairs; p += stride) {
        int a0 = pairs[2 * p], a1 = pairs[2 * p + 1];
        vfloat4 A = atoms[a0];
        vfloat4 B = atoms[a1];
        float dx = A.x - B.x, dy = A.y - B.y, dz = A.z - B.z;
        float dist = sqrtf(dx * dx + dy * dy + dz * dz + 1e-12f);
        float base = (A.w + B.w) - dist;
        if (base + tmax > 0.0f) {
#pragma unroll
            for (int c = 0; c < N_CLASS_C; ++c) {
                if (masks[(size_t)c * n_pairs + p])
                    s[c] += fmaxf(base + tc[c], 0.0f);
            }
        }
    }

    block_reduce_accum(s, accum);
}

// Phase B: mask reads for the compacted qualifying groups only.
__global__ __launch_bounds__(256) void phaseB(
    const int* __restrict__ masks,
    const float* __restrict__ tol,
    const int* __restrict__ gidx,
    const vfloat4* __restrict__ base4,
    const unsigned* __restrict__ counter,
    unsigned cap,
    float* __restrict__ accum,
    int n_pairs) {
    float tc[N_CLASS_C];
#pragma unroll
    for (int c = 0; c < N_CLASS_C; ++c) tc[c] = tol[c];

    float s[N_CLASS_C];
#pragma unroll
    for (int c = 0; c < N_CLASS_C; ++c) s[c] = 0.0f;

    unsigned count = *counter;
    if (count > cap) count = cap;
    const unsigned tid = blockIdx.x * blockDim.x + threadIdx.x;
    const unsigned stride = gridDim.x * blockDim.x;

    for (unsigned i = tid; i < count; i += stride) {
        int g = gidx[i];
        vfloat4 b = base4[i];
#pragma unroll
        for (int c = 0; c < N_CLASS_C; ++c) {
            vint4 mm = __builtin_nontemporal_load(
                &reinterpret_cast<const vint4*>(masks + (size_t)c * n_pairs)[g]);
            float acc = 0.0f;
            if (mm.x) acc += fmaxf(b.x + tc[c], 0.0f);
            if (mm.y) acc += fmaxf(b.y + tc[c], 0.0f);
            if (mm.z) acc += fmaxf(b.z + tc[c], 0.0f);
            if (mm.w) acc += fmaxf(b.w + tc[c], 0.0f);
            s[c] += acc;
        }
    }

    block_reduce_accum(s, accum);
}

__global__ void finalize(const float* __restrict__ accum,
                         const float* __restrict__ w,
                         float* __restrict__ out) {
    int c = threadIdx.x;
    if (c < N_CLASS_C) {
        float scale = expf(w[0]);
        out[c] = accum[c] * scale;
    }
}

// -------- fallback (tiny ws): direct single-kernel path --------
__global__ __launch_bounds__(256) void clash_fallback(
    const int* __restrict__ pairs,
    const float* __restrict__ coords,
    const float* __restrict__ radii,
    const int* __restrict__ names,
    const int* __restrict__ masks,
    const float* __restrict__ tol,
    float* __restrict__ accum,
    int n_pairs) {
    float tc[N_CLASS_C];
#pragma unroll
    for (int c = 0; c < N_CLASS_C; ++c) tc[c] = tol[c];
    float tmax = tc[0];
#pragma unroll
    for (int c = 1; c < N_CLASS_C; ++c) tmax = fmaxf(tmax, tc[c]);
    float s[N_CLASS_C];
#pragma unroll
    for (int c = 0; c < N_CLASS_C; ++c) s[c] = 0.0f;

    const int tid = blockIdx.x * blockDim.x + threadIdx.x;
    const int stride = gridDim.x * blockDim.x;
    for (int p = tid; p < n_pairs; p += stride) {
        int a0 = pairs[2 * p], a1 = pairs[2 * p + 1];
        float ax = coords[3 * a0], ay = coords[3 * a0 + 1], az = coords[3 * a0 + 2];
        float ar = radii[names[a0]];
        float bx = coords[3 * a1], by = coords[3 * a1 + 1], bz = coords[3 * a1 + 2];
        float br = radii[names[a1]];
        float dx = ax - bx, dy = ay - by, dz = az - bz;
        float dist = sqrtf(dx * dx + dy * dy + dz * dz + 1e-12f);
        float base = (ar + br) - dist;
        if (base + tmax > 0.0f) {
#pragma unroll
            for (int c = 0; c < N_CLASS_C; ++c) {
                if (masks[(size_t)c * n_pairs + p])
                    s[c] += fmaxf(base + tc[c], 0.0f);
            }
        }
    }
    block_reduce_accum(s, accum);
}

extern "C" void kernel_launch(void* const* d_in, const int* in_sizes, int n_in,
                              void* d_out, int out_size, void* d_ws, size_t ws_size,
                              hipStream_t stream) {
    const float* coords = (const float*)d_in[0];
    const float* radii  = (const float*)d_in[1];
    const float* tol    = (const float*)d_in[2];
    const float* weight = (const float*)d_in[3];
    const int* names    = (const int*)d_in[4];
    const int* pairs    = (const int*)d_in[5];
    const int* masks    = (const int*)d_in[6];
    float* out = (float*)d_out;

    int n_atoms = in_sizes[4];
    int n_pairs = in_sizes[5] / 2;

    const size_t hdr_bytes = 256;
    size_t atoms_bytes = ((size_t)n_atoms * sizeof(vfloat4) + 255) & ~(size_t)255;

    // list capacity from remaining ws
    size_t list_off = hdr_bytes + atoms_bytes;
    size_t cap = 0;
    if (ws_size > list_off + 1024) {
        size_t avail = ws_size - list_off - 64;
        cap = avail / (sizeof(int) + sizeof(vfloat4));  // 20 B per entry
        cap &= ~(size_t)63;
    }

    if (cap >= 4096) {
        float* accum = (float*)d_ws;
        unsigned* counter = (unsigned*)((char*)d_ws + 24);
        vfloat4* atoms = (vfloat4*)((char*)d_ws + hdr_bytes);
        int* gidx = (int*)((char*)d_ws + list_off);
        size_t b4_off = (list_off + cap * sizeof(int) + 15) & ~(size_t)15;
        vfloat4* base4 = (vfloat4*)((char*)d_ws + b4_off);

        prep_atoms<<<(n_atoms + 255) / 256, 256, 0, stream>>>(coords, radii, names, atoms, n_atoms);
        zero_hdr<<<1, 64, 0, stream>>>(accum, counter);
        int ngroups = n_pairs >> 2;
        int blocksA = (ngroups + 255) / 256;
        if (blocksA > 8192) blocksA = 8192;
        if (blocksA < 1) blocksA = 1;
        phaseA<<<blocksA, 256, 0, stream>>>(pairs, atoms, masks, tol, accum, counter,
                                            gidx, base4, (unsigned)cap, n_pairs);
        phaseB<<<128, 256, 0, stream>>>(masks, tol, gidx, base4, counter,
                                        (unsigned)cap, accum, n_pairs);
        finalize<<<1, 64, 0, stream>>>(accum, weight, out);
    } else {
        // ws too small: direct single-kernel path, accumulate in d_out.
        float* accum = out;
        zero_hdr<<<1, 64, 0, stream>>>(accum, (unsigned*)((char*)d_ws));
        clash_fallback<<<2048, 256, 0, stream>>>(pairs, coords, radii, names,
                                                 masks, tol, accum, n_pairs);
        finalize<<<1, 64, 0, stream>>>(accum, weight, out);
    }
}

// Round 4
// 54.110 us; speedup vs baseline: 2.2875x; 2.2875x over previous
//
#include <hip/hip_runtime.h>
#include <hip/hip_fp16.h>

#define N_CLASS_C 6

typedef int vint4 __attribute__((ext_vector_type(4)));

// 8-byte packed atom record: fp16 x,y,z,radius. One dwordx2 gather per atom.
struct alignas(8) HAtom {
    __half x, y, z, r;
};

__global__ void zero_accum(float* accum) {
    if (threadIdx.x < N_CLASS_C) accum[threadIdx.x] = 0.0f;
}

__global__ void prep_atoms(const float* __restrict__ coords,
                           const float* __restrict__ radii,
                           const int* __restrict__ names,
                           HAtom* __restrict__ atoms,
                           int n_atoms) {
    int i = blockIdx.x * blockDim.x + threadIdx.x;
    if (i < n_atoms) {
        HAtom a;
        a.x = __float2half(coords[3 * i + 0]);
        a.y = __float2half(coords[3 * i + 1]);
        a.z = __float2half(coords[3 * i + 2]);
        a.r = __float2half(radii[names[i]]);
        atoms[i] = a;
    }
}

__device__ __forceinline__ void block_reduce_accum(float* s, float* accum) {
    __shared__ float sh[N_CLASS_C];
    if (threadIdx.x < N_CLASS_C) sh[threadIdx.x] = 0.0f;
    __syncthreads();
#pragma unroll
    for (int c = 0; c < N_CLASS_C; ++c) {
        float v = s[c];
#pragma unroll
        for (int off = 32; off > 0; off >>= 1) v += __shfl_down(v, off, 64);
        if ((threadIdx.x & 63) == 0 && v != 0.0f) atomicAdd(&sh[c], v);
    }
    __syncthreads();
    if (threadIdx.x < N_CLASS_C) {
        float v = sh[threadIdx.x];
        if (v != 0.0f) atomicAdd(&accum[threadIdx.x], v);
    }
}

__device__ __forceinline__ float hdist_base(const HAtom& A, const HAtom& B) {
    float dx = __half2float(A.x) - __half2float(B.x);
    float dy = __half2float(A.y) - __half2float(B.y);
    float dz = __half2float(A.z) - __half2float(B.z);
    float dist = sqrtf(dx * dx + dy * dy + dz * dz + 1e-12f);
    return (__half2float(A.r) + __half2float(B.r)) - dist;
}

// Main kernel: each thread owns 4 groups (16 pairs), fully unrolled so all
// pair loads and all 32 atom gathers are independent in-flight loads (MLP).
// Groups are strided by T so pair loads stay coalesced across lanes.
__global__ __launch_bounds__(256) void clash_main(
    const int* __restrict__ pairs,      // 2 * n_pairs
    const HAtom* __restrict__ atoms,
    const int* __restrict__ masks,      // N_CLASS * n_pairs
    const float* __restrict__ tol,
    float* __restrict__ accum,
    int n_pairs, int T, int ngroups) {
    float tc[N_CLASS_C];
#pragma unroll
    for (int c = 0; c < N_CLASS_C; ++c) tc[c] = tol[c];
    float tmax = tc[0];
#pragma unroll
    for (int c = 1; c < N_CLASS_C; ++c) tmax = fmaxf(tmax, tc[c]);

    float s[N_CLASS_C];
#pragma unroll
    for (int c = 0; c < N_CLASS_C; ++c) s[c] = 0.0f;

    const int tid = blockIdx.x * blockDim.x + threadIdx.x;
    const vint4* pairs4 = reinterpret_cast<const vint4*>(pairs);

    if (tid < T) {
        int gg[4];
#pragma unroll
        for (int k = 0; k < 4; ++k) gg[k] = tid + k * T;

        vint4 pa[4], pb[4];
#pragma unroll
        for (int k = 0; k < 4; ++k) {
            pa[k] = pairs4[2 * gg[k]];
            pb[k] = pairs4[2 * gg[k] + 1];
        }

        HAtom A[4][4], B[4][4];
#pragma unroll
        for (int k = 0; k < 4; ++k) {
            int i0[4] = {pa[k].x, pa[k].z, pb[k].x, pb[k].z};
            int i1[4] = {pa[k].y, pa[k].w, pb[k].y, pb[k].w};
#pragma unroll
            for (int j = 0; j < 4; ++j) {
                A[k][j] = atoms[i0[j]];
                B[k][j] = atoms[i1[j]];
            }
        }

#pragma unroll
        for (int k = 0; k < 4; ++k) {
            float base[4];
#pragma unroll
            for (int j = 0; j < 4; ++j) base[j] = hdist_base(A[k][j], B[k][j]);
            float bm = fmaxf(fmaxf(base[0], base[1]), fmaxf(base[2], base[3]));
            if (bm + tmax > 0.0f) {   // per-lane branch: ~2% of lanes
                int g = gg[k];
#pragma unroll
                for (int c = 0; c < N_CLASS_C; ++c) {
                    const int* mrow = masks + (size_t)c * n_pairs + 4 * (size_t)g;
                    float acc = 0.0f;
                    if (mrow[0]) acc += fmaxf(base[0] + tc[c], 0.0f);
                    if (mrow[1]) acc += fmaxf(base[1] + tc[c], 0.0f);
                    if (mrow[2]) acc += fmaxf(base[2] + tc[c], 0.0f);
                    if (mrow[3]) acc += fmaxf(base[3] + tc[c], 0.0f);
                    s[c] += acc;
                }
            }
        }
    }

    // Leftover groups [4T, ngroups)
    {
        int g = 4 * T + tid;
        if (g < ngroups) {
            vint4 pa = pairs4[2 * g];
            vint4 pb = pairs4[2 * g + 1];
            int i0[4] = {pa.x, pa.z, pb.x, pb.z};
            int i1[4] = {pa.y, pa.w, pb.y, pb.w};
            float base[4];
#pragma unroll
            for (int j = 0; j < 4; ++j) base[j] = hdist_base(atoms[i0[j]], atoms[i1[j]]);
            float bm = fmaxf(fmaxf(base[0], base[1]), fmaxf(base[2], base[3]));
            if (bm + tmax > 0.0f) {
#pragma unroll
                for (int c = 0; c < N_CLASS_C; ++c) {
                    const int* mrow = masks + (size_t)c * n_pairs + 4 * (size_t)g;
                    float acc = 0.0f;
                    if (mrow[0]) acc += fmaxf(base[0] + tc[c], 0.0f);
                    if (mrow[1]) acc += fmaxf(base[1] + tc[c], 0.0f);
                    if (mrow[2]) acc += fmaxf(base[2] + tc[c], 0.0f);
                    if (mrow[3]) acc += fmaxf(base[3] + tc[c], 0.0f);
                    s[c] += acc;
                }
            }
        }
    }

    // Leftover pairs [4*ngroups, n_pairs)
    {
        int p = 4 * ngroups + tid;
        if (p < n_pairs) {
            int a0 = pairs[2 * p], a1 = pairs[2 * p + 1];
            float base = hdist_base(atoms[a0], atoms[a1]);
            if (base + tmax > 0.0f) {
#pragma unroll
                for (int c = 0; c < N_CLASS_C; ++c) {
                    if (masks[(size_t)c * n_pairs + p])
                        s[c] += fmaxf(base + tc[c], 0.0f);
                }
            }
        }
    }

    block_reduce_accum(s, accum);
}

__global__ void finalize(const float* __restrict__ accum,
                         const float* __restrict__ w,
                         float* __restrict__ out) {
    int c = threadIdx.x;
    if (c < N_CLASS_C) {
        float scale = expf(w[0]);
        out[c] = accum[c] * scale;
    }
}

// -------- fallback (tiny ws): direct gather path, fp32, no atoms table --------
__global__ __launch_bounds__(256) void clash_fallback(
    const int* __restrict__ pairs,
    const float* __restrict__ coords,
    const float* __restrict__ radii,
    const int* __restrict__ names,
    const int* __restrict__ masks,
    const float* __restrict__ tol,
    float* __restrict__ accum,
    int n_pairs) {
    float tc[N_CLASS_C];
#pragma unroll
    for (int c = 0; c < N_CLASS_C; ++c) tc[c] = tol[c];
    float tmax = tc[0];
#pragma unroll
    for (int c = 1; c < N_CLASS_C; ++c) tmax = fmaxf(tmax, tc[c]);
    float s[N_CLASS_C];
#pragma unroll
    for (int c = 0; c < N_CLASS_C; ++c) s[c] = 0.0f;

    const int tid = blockIdx.x * blockDim.x + threadIdx.x;
    const int stride = gridDim.x * blockDim.x;
    for (int p = tid; p < n_pairs; p += stride) {
        int a0 = pairs[2 * p], a1 = pairs[2 * p + 1];
        float dx = coords[3 * a0] - coords[3 * a1];
        float dy = coords[3 * a0 + 1] - coords[3 * a1 + 1];
        float dz = coords[3 * a0 + 2] - coords[3 * a1 + 2];
        float dist = sqrtf(dx * dx + dy * dy + dz * dz + 1e-12f);
        float base = (radii[names[a0]] + radii[names[a1]]) - dist;
        if (base + tmax > 0.0f) {
#pragma unroll
            for (int c = 0; c < N_CLASS_C; ++c) {
                if (masks[(size_t)c * n_pairs + p])
                    s[c] += fmaxf(base + tc[c], 0.0f);
            }
        }
    }
    block_reduce_accum(s, accum);
}

extern "C" void kernel_launch(void* const* d_in, const int* in_sizes, int n_in,
                              void* d_out, int out_size, void* d_ws, size_t ws_size,
                              hipStream_t stream) {
    const float* coords = (const float*)d_in[0];
    const float* radii  = (const float*)d_in[1];
    const float* tol    = (const float*)d_in[2];
    const float* weight = (const float*)d_in[3];
    const int* names    = (const int*)d_in[4];
    const int* pairs    = (const int*)d_in[5];
    const int* masks    = (const int*)d_in[6];
    float* out = (float*)d_out;

    int n_atoms = in_sizes[4];
    int n_pairs = in_sizes[5] / 2;

    const size_t hdr_bytes = 256;
    size_t atoms_bytes = (size_t)n_atoms * sizeof(HAtom);

    if (ws_size >= hdr_bytes + atoms_bytes) {
        float* accum = (float*)d_ws;
        HAtom* atoms = (HAtom*)((char*)d_ws + hdr_bytes);

        prep_atoms<<<(n_atoms + 255) / 256, 256, 0, stream>>>(coords, radii, names, atoms, n_atoms);
        zero_accum<<<1, 64, 0, stream>>>(accum);

        int ngroups = n_pairs >> 2;
        int T = ngroups >> 2;              // threads in main phase (4 groups each)
        int nthreads = T > 0 ? T : 256;    // ensure tail coverage for tiny inputs
        int blocks = (nthreads + 255) / 256;
        clash_main<<<blocks, 256, 0, stream>>>(pairs, atoms, masks, tol, accum,
                                               n_pairs, T, ngroups);
        finalize<<<1, 64, 0, stream>>>(accum, weight, out);
    } else {
        float* accum = out;
        zero_accum<<<1, 64, 0, stream>>>(accum);
        clash_fallback<<<2048, 256, 0, stream>>>(pairs, coords, radii, names,
                                                 masks, tol, accum, n_pairs);
        finalize<<<1, 64, 0, stream>>>(accum, weight, out);
    }
}